// Round 4
// baseline (351.841 us; speedup 1.0000x reference)
//
#include <hip/hip_runtime.h>
#include <hip/hip_cooperative_groups.h>

namespace cg = cooperative_groups;

// ---------------------------------------------------------------------------
// GeometricSuperpositionSearch (all fp32): the reference collapses to
//   new[b,n,l] = sum_j x[b,n,j] * comb[b][j^l] * sign(j^l, j)
// where comb[b] is a single 16-component multivector per batch.
//
// R8: cooperative fusion, done right this time.
//  R6's 300us failure: 32 floats of prefetch held in REGISTERS across
//  grid.sync() -> 55 MB scratch spill (WRITE 88MB, VALUBusy 1.3%). The
//  sync/fence structure itself passed verification.
//  Fix: carry the slab across the sync in LDS.
//   - phase 1: each block reduces its 512-row slab AND stages it to LDS
//     (ds_write as a side effect of the load -> single global read of cpu)
//   - block 0 overlays K2 scratch on its slab (union); it re-reads its own
//     32 KiB from L2 in phase 3
//   - phase 3: apply the signed-permutation operator from LDS, write out
//  LDS = 32K slab(U K2Shared 16K) + 4K red = 36.9K -> exactly 4 blocks/CU
//  -> 1024-block cooperative grid co-resident. No regs live across sync.
// RNG: jax partitionable threefry: counter (0, t), key (0, 42),
// bits = x0 ^ x1.  (Verified: absmax 3.9e-3.)
// Fallback on cooperative-launch error: R7's verified 3-kernel path.
// ---------------------------------------------------------------------------

#define B_ 8
#define N_ 65536
#define D_ 16
#define K_ 8
#define M_ 8
#define HID_ 64
#define BLK_PER_B 128                    // slabs per batch
#define ROWS_PER_BLK (N_ / BLK_PER_B)    // 512 rows -> 2048 float4 per slab
#define GRID_ (B_ * BLK_PER_B)           // 1024 blocks = 4 per CU

// ---- compile-time Cayley sign table: SGN.v[a][b] = sign of e_a * e_b -> e_{a^b}
struct SgnTab { float v[16][16]; };
constexpr SgnTab make_sgn() {
  SgnTab t{};
  for (int a = 0; a < 16; a++)
    for (int b = 0; b < 16; b++) {
      float s = 1.0f;
      for (int i = 0; i < 4; i++)
        if ((b >> i) & 1) {
          int h = a >> (i + 1), pc = 0;
          for (int q = 0; q < 4; q++) pc += (h >> q) & 1;
          if (pc & 1) s = -s;
          if ((a >> i) & 1) s *= (i == 0 ? 0.0f : 1.0f);  // metric {0,1,1,1}
        }
      t.v[a][b] = s;
    }
  return t;
}
constexpr SgnTab SGN = make_sgn();

// ---- threefry2x32-20, exactly as in jax/_src/prng.py ----
__device__ __forceinline__ unsigned rotl32(unsigned x, int n) {
  return (x << n) | (x >> (32 - n));
}
__device__ void threefry2x32(unsigned k0, unsigned k1, unsigned& x0, unsigned& x1) {
  unsigned ks0 = k0, ks1 = k1, ks2 = k0 ^ k1 ^ 0x1BD11BDAu;
  x0 += ks0; x1 += ks1;
  const int rotA[4] = {13, 15, 26, 6};
  const int rotB[4] = {17, 29, 16, 24};
#define TF_R4(rot)                                      \
  _Pragma("unroll")                                     \
  for (int r = 0; r < 4; r++) {                         \
    x0 += x1; x1 = rotl32(x1, rot[r]); x1 ^= x0;        \
  }
  TF_R4(rotA); x0 += ks1; x1 += ks2 + 1u;
  TF_R4(rotB); x0 += ks2; x1 += ks0 + 2u;
  TF_R4(rotA); x0 += ks0; x1 += ks1 + 3u;
  TF_R4(rotB); x0 += ks1; x1 += ks2 + 4u;
  TF_R4(rotA); x0 += ks2; x1 += ks0 + 5u;
#undef TF_R4
}

__device__ __forceinline__ void apply_row(const float cb[16], const float x[16],
                                          float o[16]) {
#pragma unroll
  for (int l = 0; l < 16; l++) {
    float acc = 0.f;
#pragma unroll
    for (int j = 0; j < 16; j++) {
      const float s = SGN.v[j ^ l][j];                  // compile-time constant
      if (s > 0.5f)       acc = fmaf(cb[j ^ l], x[j], acc);
      else if (s < -0.5f) acc = fmaf(-cb[j ^ l], x[j], acc);
    }
    o[l] = acc;
  }
}

__device__ __forceinline__ void store_row(float* __restrict__ out, size_t row,
                                          const float o[16]) {
  float4* q = (float4*)(out + row * D_);
  q[0] = make_float4(o[0],  o[1],  o[2],  o[3]);
  q[1] = make_float4(o[4],  o[5],  o[6],  o[7]);
  q[2] = make_float4(o[8],  o[9],  o[10], o[11]);
  q[3] = make_float4(o[12], o[13], o[14], o[15]);
}

// ---------------------------------------------------------------------------
// K2 scratch (16288 B) — in the fused kernel this overlays block 0's slab.
// ---------------------------------------------------------------------------
struct K2Shared {
  float summary[8][16], rs[8][16], gn[8][5], h[8][64], sc[8][8];
  float instr[8][8][16], g64[64], wts[8][8];
  float redA[8][16][16];  // [b][seg][d]
};
static_assert(sizeof(K2Shared) <= 32768, "K2Shared must fit the slab region");

__device__ __forceinline__ void k2_prelude(K2Shared& S, int t,
                                           const float* __restrict__ rulemem) {
  if (t < 128) {
    const int bb = t >> 4, d = t & 15;
    float rsum = 0.f;
    for (int m = 0; m < M_; m++) rsum += rulemem[(bb * M_ + m) * 16 + d];
    S.rs[bb][d] = rsum * (1.0f / (float)M_);
  }
  if (t < 64) {   // partitionable threefry gumbel: counter (0, t), key (0, 42)
    unsigned x0 = 0u, x1 = (unsigned)t;
    threefry2x32(0u, 42u, x0, x1);
    unsigned bits = x0 ^ x1;
    float f01 = __uint_as_float((bits >> 9) | 0x3f800000u) - 1.0f;
    float u = fmaxf(1e-6f, f01 * (1.0f - 2e-6f) + 1e-6f);
    S.g64[t] = -logf(-logf(u));
  }
}

__device__ void k2_body(K2Shared& S, int t,
                        const float* __restrict__ partial,
                        const float* __restrict__ ctrl,
                        const float* __restrict__ templates,
                        const float* __restrict__ W1,
                        const float* __restrict__ b1,
                        const float* __restrict__ W2,
                        const float* __restrict__ b2,
                        const float* __restrict__ Wr,
                        const float* __restrict__ br,
                        const float* __restrict__ logt,
                        float* __restrict__ comb) {
  // A: reduce partial[8][128][16]. flat idx = c*256+t: b = c>>3, d = t&15.
  {
    float acc[8];
#pragma unroll
    for (int q = 0; q < 8; q++) acc[q] = 0.f;
#pragma unroll
    for (int c = 0; c < 64; c++)
      acc[c >> 3] += partial[c * 256 + t];   // 64 coalesced, independent loads
#pragma unroll
    for (int q = 0; q < 8; q++) S.redA[q][t >> 4][t & 15] = acc[q];
  }
  __syncthreads();
  if (t < 128) {
    const int bb = t >> 4, d = t & 15;
    float s = 0.f;
#pragma unroll
    for (int g = 0; g < 16; g++) s += S.redA[bb][g][d];
    S.summary[bb][d] = s * (1.0f / (float)N_);
  }
  __syncthreads();
  // B: grade norms
  if (t < 40) {
    const int bb = t / 5, g = t % 5;
    float s = 0.f;
    for (int d = 0; d < 16; d++)
      if (__popc(d) == g) { float v = S.summary[bb][d]; s += v * v; }
    S.gn[bb][g] = sqrtf(s + 1e-12f);
  }
  __syncthreads();
  // C1: hidden layer [8][64]
  for (int idx = t; idx < B_ * HID_; idx += 256) {
    const int bb = idx >> 6, j = idx & 63;
    float a = b1[j];
    for (int i = 0; i < 9; i++) {
      float in = (i < 5) ? S.gn[bb][i] : ctrl[bb * 4 + (i - 5)];
      a += in * W1[i * HID_ + j];
    }
    S.h[bb][j] = fmaxf(a, 0.f);
  }
  __syncthreads();
  // C2: scores [8][8]
  if (t < 64) {
    const int bb = t >> 3, k = t & 7;
    float a = b2[k];
    for (int j = 0; j < HID_; j++) a += S.h[bb][j] * W2[j * K_ + k];
    S.sc[bb][k] = a;
  }
  __syncthreads();
  // D: instructions [8][8][16] = scores * (templates + rule_mod)
  for (int idx = t; idx < B_ * K_ * 16; idx += 256) {
    const int bb = idx >> 7, k = (idx >> 4) & 7, d = idx & 15;
    float a = br[k * 16 + d];
    for (int j = 0; j < 16; j++) a += S.rs[bb][j] * Wr[j * 128 + k * 16 + d];
    S.instr[bb][k][d] = S.sc[bb][k] * (templates[k * 16 + d] + a);
  }
  // weights: softmax((scores+g)/tau)
  if (t < 8) {
    float lt = logt[0];
    float tau = fminf(fmaxf(expf(lt), 0.1f), 5.0f);
    float z[8], m = -1e30f;
    for (int k = 0; k < 8; k++) {
      z[k] = (S.sc[t][k] + S.g64[t * 8 + k]) / tau;
      m = fmaxf(m, z[k]);
    }
    float ssum = 0.f;
    for (int k = 0; k < 8; k++) { z[k] = expf(z[k] - m); ssum += z[k]; }
    for (int k = 0; k < 8; k++) S.wts[t][k] = z[k] / ssum;
  }
  __syncthreads();
  // F: comb[b][i] = sum_k w * instr
  if (t < 128) {
    const int bb = t >> 4, i = t & 15;
    float s = 0.f;
    for (int k = 0; k < 8; k++) s += S.wts[bb][k] * S.instr[bb][k][i];
    comb[bb * 16 + i] = s;
  }
}

// ---------------------------------------------------------------------------
// fused cooperative kernel: grid = 1024 x 256, 4 blocks/CU co-resident.
// LDS: ubuf 32K (slab, overlaid by K2Shared in block 0) + red 4K = 36.9K.
// ---------------------------------------------------------------------------
__global__ __launch_bounds__(256, 4) void fused(
    const float* __restrict__ cpu,       // [8,65536,16]
    const float* __restrict__ ctrl,      // [8,4]
    const float* __restrict__ rulemem,   // [8,8,16]
    const float* __restrict__ templates, // [8,16]
    const float* __restrict__ W1,        // [9,64]
    const float* __restrict__ b1,        // [64]
    const float* __restrict__ W2,        // [64,8]
    const float* __restrict__ b2,        // [8]
    const float* __restrict__ Wr,        // [16,128]
    const float* __restrict__ br,        // [128]
    const float* __restrict__ logt,      // [1]
    float* __restrict__ partial,         // ws: [8*128*16]
    float* __restrict__ comb,            // ws: [8*16]
    float* __restrict__ out) {           // [8,65536,16]
  cg::grid_group grid = cg::this_grid();
  const int t = threadIdx.x;
  const int bid = blockIdx.x;
  const int b = bid >> 7;            // batch (wave-uniform)
  const int blk = bid & 127;         // slab within batch

  __shared__ __align__(16) char ubuf[32768];   // slab[2048] float4  U  K2Shared
  __shared__ float red[256 * 4];
  float4* slab = (float4*)ubuf;
  K2Shared& S = *(K2Shared*)ubuf;

  const float4* base =
      (const float4*)(cpu + (((size_t)b << 16) + (size_t)blk * ROWS_PER_BLK) * D_);

  // -------- Phase 1: reduce slab + stage it into LDS (single global read) ---
  {
    float a0 = 0.f, a1 = 0.f, a2 = 0.f, a3 = 0.f;
#pragma unroll
    for (int i = 0; i < (ROWS_PER_BLK * 4) / 256; i++) {   // 8 iters
      float4 v = base[i * 256 + t];
      slab[i * 256 + t] = v;                  // LDS stash (persists across sync)
      a0 += v.x; a1 += v.y; a2 += v.z; a3 += v.w;
    }
    red[t * 4 + 0] = a0; red[t * 4 + 1] = a1;
    red[t * 4 + 2] = a2; red[t * 4 + 3] = a3;
    __syncthreads();                          // slab + red complete
    if (t < 16) {
      const int c = t >> 2, j = t & 3;        // component d = 4c + j = t
      float s = 0.f;
#pragma unroll
      for (int m = 0; m < 64; m++) s += red[(c + 4 * m) * 4 + j];
      partial[((size_t)b * BLK_PER_B + blk) * 16 + t] = s;
    }
  }
  // block 0: k2 pieces with no phase-1 dependency (clobbers ITS slab only;
  // block 0 re-reads its 32 KiB from L2 in phase 3)
  if (bid == 0) k2_prelude(S, t, rulemem);

  __threadfence();
  grid.sync();

  // -------- Phase 2: block 0 computes comb[8][16] ---------------------------
  if (bid == 0) {
    k2_body(S, t, partial, ctrl, templates, W1, b1, W2, b2, Wr, br, logt, comb);
    __threadfence();
  }
  grid.sync();

  // -------- Phase 3: apply signed-permutation operator ----------------------
  float cb[16];
  {
    const float* cp = comb + b * 16;
#pragma unroll
    for (int i = 0; i < 16; i++) cb[i] = cp[i];          // uniform
  }
  const size_t orow = ((size_t)b << 16) + (size_t)blk * ROWS_PER_BLK;

  if (bid == 0) {
    // slab was overlaid by K2Shared: re-read from global (L1/L2-hot, 32 KiB)
#pragma unroll
    for (int rr = 0; rr < 2; rr++) {
      const int r = t + rr * 256;
      const float4* p = base + r * 4;
      float4 v0 = p[0], v1 = p[1], v2 = p[2], v3 = p[3];
      float x[16] = {v0.x, v0.y, v0.z, v0.w, v1.x, v1.y, v1.z, v1.w,
                     v2.x, v2.y, v2.z, v2.w, v3.x, v3.y, v3.z, v3.w};
      float o[16];
      apply_row(cb, x, o);
      store_row(out, orow + r, o);
    }
  } else {
#pragma unroll
    for (int rr = 0; rr < 2; rr++) {
      const int r = t + rr * 256;
      float4 v0 = slab[r * 4 + 0], v1 = slab[r * 4 + 1];
      float4 v2 = slab[r * 4 + 2], v3 = slab[r * 4 + 3];
      float x[16] = {v0.x, v0.y, v0.z, v0.w, v1.x, v1.y, v1.z, v1.w,
                     v2.x, v2.y, v2.z, v2.w, v3.x, v3.y, v3.z, v3.w};
      float o[16];
      apply_row(cb, x, o);
      store_row(out, orow + r, o);
    }
  }
}

// ---------------------------------------------------------------------------
// Fallback path: R7's harness-verified 3-kernel structure (plain launches),
// used only if hipLaunchCooperativeKernel returns an error.
// ---------------------------------------------------------------------------
__global__ __launch_bounds__(256) void k1_reduce(
    const float* __restrict__ cpu, float* __restrict__ partial) {
  const int b = blockIdx.y, blk = blockIdx.x, t = threadIdx.x;
  const float4* base =
      (const float4*)(cpu + (((size_t)b << 16) + (size_t)blk * ROWS_PER_BLK) * D_);
  float a0 = 0.f, a1 = 0.f, a2 = 0.f, a3 = 0.f;
#pragma unroll
  for (int i = 0; i < (ROWS_PER_BLK * 4) / 256; i++) {   // 8 iters
    float4 v = base[i * 256 + t];
    a0 += v.x; a1 += v.y; a2 += v.z; a3 += v.w;
  }
  __shared__ float red[256 * 4];
  red[t * 4 + 0] = a0; red[t * 4 + 1] = a1;
  red[t * 4 + 2] = a2; red[t * 4 + 3] = a3;
  __syncthreads();
  if (t < 16) {
    const int c = t >> 2, j = t & 3;
    float s = 0.f;
#pragma unroll
    for (int m = 0; m < 64; m++) s += red[(c + 4 * m) * 4 + j];
    partial[((size_t)b * BLK_PER_B + blk) * 16 + t] = s;
  }
}

__global__ __launch_bounds__(256) void k2_small(
    const float* __restrict__ partial, const float* __restrict__ ctrl,
    const float* __restrict__ rulemem, const float* __restrict__ templates,
    const float* __restrict__ W1, const float* __restrict__ b1,
    const float* __restrict__ W2, const float* __restrict__ b2,
    const float* __restrict__ Wr, const float* __restrict__ br,
    const float* __restrict__ logt, float* __restrict__ comb) {
  const int t = threadIdx.x;
  __shared__ K2Shared S;
  k2_prelude(S, t, rulemem);
  __syncthreads();
  k2_body(S, t, partial, ctrl, templates, W1, b1, W2, b2, Wr, br, logt, comb);
}

__global__ __launch_bounds__(256) void k3_apply(
    const float* __restrict__ cpu, const float* __restrict__ comb,
    float* __restrict__ out) {
  const int b = blockIdx.x >> 8;                       // wave-uniform
  const int rowInB = ((blockIdx.x & 255) << 8) + threadIdx.x;
  const size_t row = ((size_t)b << 16) + (size_t)rowInB;

  float cb[16];
  const float* cp = comb + b * 16;
#pragma unroll
  for (int i = 0; i < 16; i++) cb[i] = cp[i];

  const float4* p = (const float4*)(cpu + row * D_);
  float4 v0 = p[0], v1 = p[1], v2 = p[2], v3 = p[3];
  float x[16] = {v0.x, v0.y, v0.z, v0.w, v1.x, v1.y, v1.z, v1.w,
                 v2.x, v2.y, v2.z, v2.w, v3.x, v3.y, v3.z, v3.w};
  float o[16];
  apply_row(cb, x, o);
  store_row(out, row, o);
}

extern "C" void kernel_launch(void* const* d_in, const int* in_sizes, int n_in,
                              void* d_out, int out_size, void* d_ws, size_t ws_size,
                              hipStream_t stream) {
  const float* cpu       = (const float*)d_in[0];
  const float* ctrl      = (const float*)d_in[1];
  const float* rulemem   = (const float*)d_in[2];
  const float* templates = (const float*)d_in[3];
  const float* W1        = (const float*)d_in[4];
  const float* b1        = (const float*)d_in[5];
  const float* W2        = (const float*)d_in[6];
  const float* b2        = (const float*)d_in[7];
  const float* Wr        = (const float*)d_in[8];
  const float* br        = (const float*)d_in[9];
  const float* logt      = (const float*)d_in[10];
  float* outp = (float*)d_out;

  // partial: 8*128*16 floats (64 KiB) + comb: 128 floats.
  float* partial = (float*)d_ws;
  float* comb;
  const size_t need = (size_t)(B_ * BLK_PER_B * 16 + B_ * 16) * sizeof(float);
  if (ws_size >= need) {
    comb = partial + (size_t)B_ * BLK_PER_B * 16;
  } else {
    // stage partial in the output buffer (fully consumed before any phase-3 /
    // k3 store; regions separated by grid.sync / kernel boundary)
    partial = outp;
    comb = (float*)d_ws;
  }

  void* args[] = {
      (void*)&cpu, (void*)&ctrl, (void*)&rulemem, (void*)&templates,
      (void*)&W1, (void*)&b1, (void*)&W2, (void*)&b2,
      (void*)&Wr, (void*)&br, (void*)&logt,
      (void*)&partial, (void*)&comb, (void*)&outp};
  hipError_t err = hipLaunchCooperativeKernel((void*)fused, dim3(GRID_),
                                              dim3(256), args, 0, stream);
  if (err != hipSuccess) {
    // R7's verified 3-kernel path.
    k1_reduce<<<dim3(BLK_PER_B, B_), 256, 0, stream>>>(cpu, partial);
    k2_small<<<1, 256, 0, stream>>>(partial, ctrl, rulemem, templates, W1, b1,
                                    W2, b2, Wr, br, logt, comb);
    k3_apply<<<2048, 256, 0, stream>>>(cpu, comb, outp);
  }
}

// Round 5
// 113.039 us; speedup vs baseline: 3.1126x; 3.1126x over previous
//
#include <hip/hip_runtime.h>

// ---------------------------------------------------------------------------
// GeometricSuperpositionSearch (all fp32): the reference collapses to
//   new[b,n,l] = sum_j x[b,n,j] * comb[b][j^l] * sign(j^l, j)
// where comb[b] is a single 16-component multivector per batch:
//   comb[b][i] = sum_k weights[b,k] * scores[b,k] * (templates[k,i] + rule_mod[b,k,i])
//
// R9: cooperative fusion abandoned for good. Evidence: R6 (register-carry,
// spills) = 300us; R8 (LDS-carry, NO spills, VGPR=64, WRITE 51MB) = 225us.
// Same ~10x-over-work time with VALUBusy ~2% in both -> the cost is the
// 1024-block grid.sync itself (global-atomic barrier across 8 non-coherent
// XCD L2s), not spill. Back to the verified 3-kernel graph.
//
// This round's change: k3 global access was 64B-strided (1 row/thread ->
// per dwordx4 a wave touches 32 cache lines instead of 8, both directions).
// New k3: coalesced tile load -> bank-swizzled LDS -> per-row compute
// (compile-time Cayley signs preserved) -> LDS -> coalesced nontemporal
// store. Swizzle slot(r,w)=r*4+(w^(r&3)^((r>>2)&3)) hits the b128 8-cycle
// bank floor on row reads.
//
// RNG: jax partitionable threefry: element t -> counter (0, t), key (0, 42),
// bits = x0 ^ x1.  (Verified: absmax 3.9e-3.)
// ---------------------------------------------------------------------------

#define B_ 8
#define N_ 65536
#define D_ 16
#define K_ 8
#define M_ 8
#define HID_ 64
#define BLK_PER_B 128                    // k1 slabs per batch
#define ROWS_PER_BLK (N_ / BLK_PER_B)    // 512 rows -> 2048 float4 per slab

typedef float f4v __attribute__((ext_vector_type(4)));

// ---- compile-time Cayley sign table: SGN.v[a][b] = sign of e_a * e_b -> e_{a^b}
struct SgnTab { float v[16][16]; };
constexpr SgnTab make_sgn() {
  SgnTab t{};
  for (int a = 0; a < 16; a++)
    for (int b = 0; b < 16; b++) {
      float s = 1.0f;
      for (int i = 0; i < 4; i++)
        if ((b >> i) & 1) {
          int h = a >> (i + 1), pc = 0;
          for (int q = 0; q < 4; q++) pc += (h >> q) & 1;
          if (pc & 1) s = -s;
          if ((a >> i) & 1) s *= (i == 0 ? 0.0f : 1.0f);  // metric {0,1,1,1}
        }
      t.v[a][b] = s;
    }
  return t;
}
constexpr SgnTab SGN = make_sgn();

// ---- threefry2x32-20, exactly as in jax/_src/prng.py ----
__device__ __forceinline__ unsigned rotl32(unsigned x, int n) {
  return (x << n) | (x >> (32 - n));
}
__device__ void threefry2x32(unsigned k0, unsigned k1, unsigned& x0, unsigned& x1) {
  unsigned ks0 = k0, ks1 = k1, ks2 = k0 ^ k1 ^ 0x1BD11BDAu;
  x0 += ks0; x1 += ks1;
  const int rotA[4] = {13, 15, 26, 6};
  const int rotB[4] = {17, 29, 16, 24};
#define TF_R4(rot)                                      \
  _Pragma("unroll")                                     \
  for (int r = 0; r < 4; r++) {                         \
    x0 += x1; x1 = rotl32(x1, rot[r]); x1 ^= x0;        \
  }
  TF_R4(rotA); x0 += ks1; x1 += ks2 + 1u;
  TF_R4(rotB); x0 += ks2; x1 += ks0 + 2u;
  TF_R4(rotA); x0 += ks0; x1 += ks1 + 3u;
  TF_R4(rotB); x0 += ks1; x1 += ks2 + 4u;
  TF_R4(rotA); x0 += ks2; x1 += ks0 + 5u;
#undef TF_R4
}

__device__ __forceinline__ void apply_row(const float cb[16], const float x[16],
                                          float o[16]) {
#pragma unroll
  for (int l = 0; l < 16; l++) {
    float acc = 0.f;
#pragma unroll
    for (int j = 0; j < 16; j++) {
      const float s = SGN.v[j ^ l][j];                  // compile-time constant
      if (s > 0.5f)       acc = fmaf(cb[j ^ l], x[j], acc);
      else if (s < -0.5f) acc = fmaf(-cb[j ^ l], x[j], acc);
    }
    o[l] = acc;
  }
}

// ---------------------------------------------------------------------------
// k1: per-(b,d) partial sums of cpu_state over a 512-row slab.
// grid (BLK_PER_B, B_) = 1024 blocks, 256 threads. Fully coalesced loads.
// ---------------------------------------------------------------------------
__global__ __launch_bounds__(256) void k1_reduce(
    const float* __restrict__ cpu, float* __restrict__ partial) {
  const int b = blockIdx.y, blk = blockIdx.x, t = threadIdx.x;
  const float4* base =
      (const float4*)(cpu + (((size_t)b << 16) + (size_t)blk * ROWS_PER_BLK) * D_);
  float a0 = 0.f, a1 = 0.f, a2 = 0.f, a3 = 0.f;
#pragma unroll
  for (int i = 0; i < (ROWS_PER_BLK * 4) / 256; i++) {   // 8 iters
    float4 v = base[i * 256 + t];
    a0 += v.x; a1 += v.y; a2 += v.z; a3 += v.w;
  }
  __shared__ float red[256 * 4];
  red[t * 4 + 0] = a0; red[t * 4 + 1] = a1;
  red[t * 4 + 2] = a2; red[t * 4 + 3] = a3;
  __syncthreads();
  if (t < 16) {
    const int c = t >> 2, j = t & 3;      // component d = 4c + j = t
    float s = 0.f;
#pragma unroll
    for (int m = 0; m < 64; m++) s += red[(c + 4 * m) * 4 + j];
    partial[((size_t)b * BLK_PER_B + blk) * 16 + t] = s;
  }
}

// ---------------------------------------------------------------------------
// k2: single block -> comb[8][16] (fp32)
// partial is [8][128][16] flat = 16384 floats.
// ---------------------------------------------------------------------------
__global__ __launch_bounds__(256) void k2_small(
    const float* __restrict__ partial,   // [8*128*16]
    const float* __restrict__ ctrl,      // [8,4]
    const float* __restrict__ rulemem,   // [8,8,16]
    const float* __restrict__ templates, // [8,16]
    const float* __restrict__ W1,        // [9,64]
    const float* __restrict__ b1,        // [64]
    const float* __restrict__ W2,        // [64,8]
    const float* __restrict__ b2,        // [8]
    const float* __restrict__ Wr,        // [16,128]
    const float* __restrict__ br,        // [128]
    const float* __restrict__ logt,     // [1]
    float* __restrict__ comb) {
  const int t = threadIdx.x;
  __shared__ float summary[8][16], rs[8][16], gn[8][5], h[8][64], sc[8][8];
  __shared__ float instr[8][8][16], g64[64], wts[8][8];
  __shared__ float redA[8][16][16];      // [b][seg][d]

  // A: cooperative load+reduce of partial.
  // flat idx = c*256 + t: b = c>>3 (exact: (c%8)*256+t < 2048), d = t&15.
  {
    float acc[8];
#pragma unroll
    for (int q = 0; q < 8; q++) acc[q] = 0.f;
#pragma unroll
    for (int c = 0; c < 64; c++)
      acc[c >> 3] += partial[c * 256 + t];   // 64 coalesced, independent loads
#pragma unroll
    for (int q = 0; q < 8; q++) redA[q][t >> 4][t & 15] = acc[q];
  }
  // rule summary + gumbel (no dependency on partial)
  if (t < 128) {
    const int bb = t >> 4, d = t & 15;
    float rsum = 0.f;
    for (int m = 0; m < M_; m++) rsum += rulemem[(bb * M_ + m) * 16 + d];
    rs[bb][d] = rsum * (1.0f / (float)M_);
  }
  if (t < 64) {   // partitionable threefry gumbel: counter (0, t), key (0, 42)
    unsigned x0 = 0u, x1 = (unsigned)t;
    threefry2x32(0u, 42u, x0, x1);
    unsigned bits = x0 ^ x1;
    float f01 = __uint_as_float((bits >> 9) | 0x3f800000u) - 1.0f;
    float u = fmaxf(1e-6f, f01 * (1.0f - 2e-6f) + 1e-6f);
    g64[t] = -logf(-logf(u));
  }
  __syncthreads();
  if (t < 128) {
    const int bb = t >> 4, d = t & 15;
    float s = 0.f;
#pragma unroll
    for (int g = 0; g < 16; g++) s += redA[bb][g][d];
    summary[bb][d] = s * (1.0f / (float)N_);
  }
  __syncthreads();
  // B: grade norms
  if (t < 40) {
    const int bb = t / 5, g = t % 5;
    float s = 0.f;
    for (int d = 0; d < 16; d++)
      if (__popc(d) == g) { float v = summary[bb][d]; s += v * v; }
    gn[bb][g] = sqrtf(s + 1e-12f);
  }
  __syncthreads();
  // C1: hidden layer [8][64]
  for (int idx = t; idx < B_ * HID_; idx += 256) {
    const int bb = idx >> 6, j = idx & 63;
    float a = b1[j];
    for (int i = 0; i < 9; i++) {
      float in = (i < 5) ? gn[bb][i] : ctrl[bb * 4 + (i - 5)];
      a += in * W1[i * HID_ + j];
    }
    h[bb][j] = fmaxf(a, 0.f);
  }
  __syncthreads();
  // C2: scores [8][8]
  if (t < 64) {
    const int bb = t >> 3, k = t & 7;
    float a = b2[k];
    for (int j = 0; j < HID_; j++) a += h[bb][j] * W2[j * K_ + k];
    sc[bb][k] = a;
  }
  __syncthreads();
  // D: instructions [8][8][16] = scores * (templates + rule_mod)
  for (int idx = t; idx < B_ * K_ * 16; idx += 256) {
    const int bb = idx >> 7, k = (idx >> 4) & 7, d = idx & 15;
    float a = br[k * 16 + d];
    for (int j = 0; j < 16; j++) a += rs[bb][j] * Wr[j * 128 + k * 16 + d];
    instr[bb][k][d] = sc[bb][k] * (templates[k * 16 + d] + a);
  }
  // weights: softmax((scores+g)/tau)
  if (t < 8) {
    float lt = logt[0];
    float tau = fminf(fmaxf(expf(lt), 0.1f), 5.0f);
    float z[8], m = -1e30f;
    for (int k = 0; k < 8; k++) {
      z[k] = (sc[t][k] + g64[t * 8 + k]) / tau;
      m = fmaxf(m, z[k]);
    }
    float ssum = 0.f;
    for (int k = 0; k < 8; k++) { z[k] = expf(z[k] - m); ssum += z[k]; }
    for (int k = 0; k < 8; k++) wts[t][k] = z[k] / ssum;
  }
  __syncthreads();
  // F: comb[b][i] = sum_k w * instr
  if (t < 128) {
    const int bb = t >> 4, i = t & 15;
    float s = 0.f;
    for (int k = 0; k < 8; k++) s += wts[bb][k] * instr[bb][k][i];
    comb[bb * 16 + i] = s;
  }
}

// ---------------------------------------------------------------------------
// k3 (R9): out[b,n,l] = sum_j x[b,n,j] * comb[b][j^l] * SGN[j^l][j]
// grid 2048 blocks x 256 threads; each block owns a 256-row tile (16 KiB).
//   1. coalesced float4 loads -> swizzled LDS     (8 lines/instr, was 32)
//   2. per-thread row read from LDS (b128 bank floor via swizzle), apply_row
//      with compile-time signs, write back in place (rows disjoint -> no
//      barrier between read and write-back)
//   3. coalesced nontemporal float4 stores from LDS
// swizzle: slot(r,w) = r*4 + (w ^ (r&3) ^ ((r>>2)&3))  (bijective per quad)
// ---------------------------------------------------------------------------
__global__ __launch_bounds__(256) void k3_apply(
    const float* __restrict__ cpu, const float* __restrict__ comb,
    float* __restrict__ out) {
  const int t = threadIdx.x;
  const int b = blockIdx.x >> 8;                    // 256 blocks per batch
  const size_t base4 = (size_t)blockIdx.x * 1024;   // float4 idx of tile start

  __shared__ float4 lds4[1024];                     // 16 KiB tile

  float cb[16];
  {
    const float* cp = comb + b * 16;
#pragma unroll
    for (int i = 0; i < 16; i++) cb[i] = cp[i];     // uniform -> s_load
  }

  const float4* in4 = (const float4*)cpu + base4;
  float4* out4 = (float4*)out + base4;

  // swizzle bits for the linear (coalesced) phases depend only on t:
  // m = i*256 + t  ->  (m>>2)&3 = (t>>2)&3,  (m>>4)&3 = (t>>4)&3
  const int sw = ((t >> 2) & 3) ^ ((t >> 4) & 3);

  // 1. coalesced load -> swizzled LDS
#pragma unroll
  for (int i = 0; i < 4; i++) {
    const int m = i * 256 + t;
    lds4[m ^ sw] = in4[m];
  }
  __syncthreads();

  // 2. own row t from LDS, compute, write back in place
  {
    const int rsw = (t & 3) ^ ((t >> 2) & 3);
    float4 q0 = lds4[t * 4 + (0 ^ rsw)];
    float4 q1 = lds4[t * 4 + (1 ^ rsw)];
    float4 q2 = lds4[t * 4 + (2 ^ rsw)];
    float4 q3 = lds4[t * 4 + (3 ^ rsw)];
    float x[16] = {q0.x, q0.y, q0.z, q0.w, q1.x, q1.y, q1.z, q1.w,
                   q2.x, q2.y, q2.z, q2.w, q3.x, q3.y, q3.z, q3.w};
    float o[16];
    apply_row(cb, x, o);
    lds4[t * 4 + (0 ^ rsw)] = make_float4(o[0],  o[1],  o[2],  o[3]);
    lds4[t * 4 + (1 ^ rsw)] = make_float4(o[4],  o[5],  o[6],  o[7]);
    lds4[t * 4 + (2 ^ rsw)] = make_float4(o[8],  o[9],  o[10], o[11]);
    lds4[t * 4 + (3 ^ rsw)] = make_float4(o[12], o[13], o[14], o[15]);
  }
  __syncthreads();

  // 3. swizzled LDS -> coalesced nontemporal store (out is never re-read)
#pragma unroll
  for (int i = 0; i < 4; i++) {
    const int m = i * 256 + t;
    f4v v = *(const f4v*)&lds4[m ^ sw];
    __builtin_nontemporal_store(v, (f4v*)&out4[m]);
  }
}

extern "C" void kernel_launch(void* const* d_in, const int* in_sizes, int n_in,
                              void* d_out, int out_size, void* d_ws, size_t ws_size,
                              hipStream_t stream) {
  const float* cpu       = (const float*)d_in[0];
  const float* ctrl      = (const float*)d_in[1];
  const float* rulemem   = (const float*)d_in[2];
  const float* templates = (const float*)d_in[3];
  const float* W1        = (const float*)d_in[4];
  const float* b1        = (const float*)d_in[5];
  const float* W2        = (const float*)d_in[6];
  const float* b2        = (const float*)d_in[7];
  const float* Wr        = (const float*)d_in[8];
  const float* br        = (const float*)d_in[9];
  const float* logt      = (const float*)d_in[10];
  float* outp = (float*)d_out;

  // partial: 8*128*16 floats (64 KiB) + comb: 128 floats.
  float* partial = (float*)d_ws;
  float* comb;
  const size_t need = (size_t)(B_ * BLK_PER_B * 16 + B_ * 16) * sizeof(float);
  if (ws_size >= need) {
    comb = partial + (size_t)B_ * BLK_PER_B * 16;
  } else {
    // stage partial in the output buffer (fully consumed by k2 before k3's
    // first store; regions separated by kernel boundaries)
    partial = outp;
    comb = (float*)d_ws;
  }

  k1_reduce<<<dim3(BLK_PER_B, B_), 256, 0, stream>>>(cpu, partial);
  k2_small<<<1, 256, 0, stream>>>(partial, ctrl, rulemem, templates, W1, b1,
                                  W2, b2, Wr, br, logt, comb);
  k3_apply<<<2048, 256, 0, stream>>>(cpu, comb, outp);
}